// Round 3
// baseline (669.375 us; speedup 1.0000x reference)
//
#include <hip/hip_runtime.h>
#include <math.h>

#define T_STEPS 1024
#define BATCH   32
#define DIM     1024
#define NST     64
#define TBN     ((size_t)T_STEPS * BATCH * NST)   // 2M elements per projection

// ======================= Phase 1: fused projection GEMM =======================
// out[m][nf] = sum_d x[m][d]*Wf[nf][d], M=32768, Nf=256 (Wk|Wv|Wq|Wa), K=1024.
// fp32 vector ALU. Tile 128(M)x128(N)x32(K), 128 threads, per-thread 16x8:
// 6 ds_read_b128 per 128 FMA (vs 4 per 64 before) -> LDS:VALU flips to ~VALU-bound.
// Grid (256,2)=512 blocks = 2 blocks/CU so barrier drains overlap.

#define MT 128
#define NT 128
#define KT 32

__global__ __launch_bounds__(128, 2)
void proj_gemm_fused(const float* __restrict__ x,
                     const float* __restrict__ Wk,
                     const float* __restrict__ Wv,
                     const float* __restrict__ Wq,
                     const float* __restrict__ Wa,
                     float* __restrict__ ws)
{
    __shared__ float As[KT][MT + 4];   // row = 132 floats = 528B (16B-aligned)
    __shared__ float Bs[KT][NT + 4];

    const int tid = threadIdx.x;
    const int m0  = blockIdx.x * MT;
    const int nb0 = blockIdx.y * NT;

    // staging ids: 8 lanes cover 32 k-floats (128B) of one row; 16 rows/pass, 8 passes
    const int lm = tid >> 3;          // 0..15
    const int lk = (tid & 7) * 4;     // 0,4,...,28

    // compute ids: 16 rows x 8 cols per thread
    const int tm = (tid >> 4) * 16;   // 0,16,...,112
    const int tn = (tid & 15) * 8;    // 0,8,...,120

    const float* arow[8];
    const float* brow[8];
    #pragma unroll
    for (int p = 0; p < 8; p++) {
        arow[p] = x + (size_t)(m0 + p * 16 + lm) * DIM + lk;
        const int ng = nb0 + p * 16 + lm;   // fused col 0..255
        const float* W = (ng < 64) ? Wk : (ng < 128) ? Wv : (ng < 192) ? Wq : Wa;
        brow[p] = W + (size_t)(ng & 63) * DIM + lk;
    }

    float acc[16][8];
    #pragma unroll
    for (int i = 0; i < 16; i++)
        #pragma unroll
        for (int j = 0; j < 8; j++) acc[i][j] = 0.f;

    for (int k0 = 0; k0 < DIM; k0 += KT) {
        __syncthreads();
        #pragma unroll
        for (int p = 0; p < 8; p++) {
            const int mm = p * 16 + lm;
            const float4 v = *(const float4*)(arow[p] + k0);
            As[lk + 0][mm] = v.x; As[lk + 1][mm] = v.y;
            As[lk + 2][mm] = v.z; As[lk + 3][mm] = v.w;
        }
        #pragma unroll
        for (int p = 0; p < 8; p++) {
            const int nn = p * 16 + lm;
            const float4 v = *(const float4*)(brow[p] + k0);
            Bs[lk + 0][nn] = v.x; Bs[lk + 1][nn] = v.y;
            Bs[lk + 2][nn] = v.z; Bs[lk + 3][nn] = v.w;
        }
        __syncthreads();

        #pragma unroll 4
        for (int kk = 0; kk < KT; kk++) {
            float a[16], b[8];
            *(float4*)&a[0]  = *(const float4*)&As[kk][tm];
            *(float4*)&a[4]  = *(const float4*)&As[kk][tm + 4];
            *(float4*)&a[8]  = *(const float4*)&As[kk][tm + 8];
            *(float4*)&a[12] = *(const float4*)&As[kk][tm + 12];
            *(float4*)&b[0]  = *(const float4*)&Bs[kk][tn];
            *(float4*)&b[4]  = *(const float4*)&Bs[kk][tn + 4];
            #pragma unroll
            for (int i = 0; i < 16; i++)
                #pragma unroll
                for (int j = 0; j < 8; j++)
                    acc[i][j] = fmaf(a[i], b[j], acc[i][j]);
        }
    }

    // epilogue: scatter into the 4 per-projection [T*B, 64] buffers
    const int ng0  = nb0 + tn;          // multiple of 8, never crosses a 64-boundary
    const int wsel = ng0 >> 6;
    const int nloc = ng0 & 63;
    float* ob = ws + (size_t)wsel * TBN + nloc;
    #pragma unroll
    for (int i = 0; i < 16; i++) {
        float* o = ob + (size_t)(m0 + tm + i) * NST;
        *(float4*)(o)     = make_float4(acc[i][0], acc[i][1], acc[i][2], acc[i][3]);
        *(float4*)(o + 4) = make_float4(acc[i][4], acc[i][5], acc[i][6], acc[i][7]);
    }
}

// ======================= Phase 2: sequential scan =======================
// 8 lanes/row, 8 cols/lane, wave = 8 rows, grid = 32 b x 8 rowgroups = 256 blocks.
// S in registers. Depth-8 register prefetch: loads issue 7 steps (~1000+ cyc) ahead
// of use -> covers LLC/HBM first-touch latency at 1 wave/CU. 42 loads in flight < 63.

__device__ __forceinline__ float dpp_add_xor1(float v) {   // quad_perm [1,0,3,2]
    int o = __builtin_amdgcn_mov_dpp(__float_as_int(v), 0xB1, 0xF, 0xF, true);
    return v + __int_as_float(o);
}
__device__ __forceinline__ float dpp_add_xor2(float v) {   // quad_perm [2,3,0,1]
    int o = __builtin_amdgcn_mov_dpp(__float_as_int(v), 0x4E, 0xF, 0xF, true);
    return v + __int_as_float(o);
}
__device__ __forceinline__ float dpp_add_half_mirror(float v) { // ROW_HALF_MIRROR
    int o = __builtin_amdgcn_mov_dpp(__float_as_int(v), 0x141, 0xF, 0xF, true);
    return v + __int_as_float(o);
}

__device__ __forceinline__ float fast_sigmoid(float z) {
    float e = __builtin_amdgcn_exp2f(z * -1.44269504088896340736f);
    return __builtin_amdgcn_rcpf(1.0f + e);
}

__global__ __launch_bounds__(64)
void scan8_kernel(const float* __restrict__ ws,
                  const float* __restrict__ S0,
                  const float* __restrict__ d_alpha,
                  const float* __restrict__ b_alpha,
                  float* __restrict__ out)
{
    const float* kb = ws;
    const float* vb = ws + TBN;
    const float* qb = ws + 2 * TBN;
    const float* ab = ws + 3 * TBN;

    const int lane = threadIdx.x;      // 0..63
    const int b    = blockIdx.x >> 3;  // batch
    const int rg   = blockIdx.x & 7;   // row group (8 rows)
    const int rl   = lane >> 3;        // row within group
    const int cg   = lane & 7;         // column group
    const int row  = rg * 8 + rl;      // 0..63
    const int c0   = cg * 8;

    float S[8];
    {
        const float* s0p = S0 + ((size_t)b * NST + row) * NST + c0;
        float4 v0 = *(const float4*)(s0p);
        float4 v1 = *(const float4*)(s0p + 4);
        S[0]=v0.x; S[1]=v0.y; S[2]=v0.z; S[3]=v0.w;
        S[4]=v1.x; S[5]=v1.y; S[6]=v1.z; S[7]=v1.w;
    }
    const float da = d_alpha[row];
    const float ba = b_alpha[row];

    const size_t stp = (size_t)BATCH * NST;   // 2048
    const float* kp = kb + (size_t)b * NST + c0;
    const float* qp = qb + (size_t)b * NST + c0;
    const float* vp = vb + (size_t)b * NST + row;
    const float* ap = ab + (size_t)b * NST + row;
    float* op = out + (size_t)b * NST + row;

    float kS[8][8], qS[8][8], vS[8], aS[8];

    auto loadStep = [&](int t, float (&kf)[8], float (&qf)[8], float& vv, float& aa) {
        const size_t off = (size_t)t * stp;
        float4 x0 = *(const float4*)(kp + off);
        float4 x1 = *(const float4*)(kp + off + 4);
        kf[0]=x0.x; kf[1]=x0.y; kf[2]=x0.z; kf[3]=x0.w;
        kf[4]=x1.x; kf[5]=x1.y; kf[6]=x1.z; kf[7]=x1.w;
        float4 y0 = *(const float4*)(qp + off);
        float4 y1 = *(const float4*)(qp + off + 4);
        qf[0]=y0.x; qf[1]=y0.y; qf[2]=y0.z; qf[3]=y0.w;
        qf[4]=y1.x; qf[5]=y1.y; qf[6]=y1.z; qf[7]=y1.w;
        vv = vp[off];
        aa = ap[off] + ba;           // fold bias at load time
    };

    auto compute = [&](int t, const float (&kf)[8], const float (&qf)[8],
                       float vv, float aa) {
        float p0 = S[0] * kf[0];
        float p1 = S[1] * kf[1];
        p0 = fmaf(S[2], kf[2], p0);  p1 = fmaf(S[3], kf[3], p1);
        p0 = fmaf(S[4], kf[4], p0);  p1 = fmaf(S[5], kf[5], p1);
        p0 = fmaf(S[6], kf[6], p0);  p1 = fmaf(S[7], kf[7], p1);
        float part = p0 + p1;
        part = dpp_add_xor1(part);
        part = dpp_add_xor2(part);
        part = dpp_add_half_mirror(part);

        const float z     = fmaf(da, part, aa);
        const float alpha = fast_sigmoid(z);
        const float w     = (1.f - alpha) * vv;

        #pragma unroll
        for (int j = 0; j < 8; j++)
            S[j] = fmaf(alpha, S[j], w * kf[j]);

        float h0 = S[0] * qf[0];
        float h1 = S[1] * qf[1];
        h0 = fmaf(S[2], qf[2], h0);  h1 = fmaf(S[3], qf[3], h1);
        h0 = fmaf(S[4], qf[4], h0);  h1 = fmaf(S[5], qf[5], h1);
        h0 = fmaf(S[6], qf[6], h0);  h1 = fmaf(S[7], qf[7], h1);
        float h = h0 + h1;
        h = dpp_add_xor1(h);
        h = dpp_add_xor2(h);
        h = dpp_add_half_mirror(h);

        const float o = h * h * fast_sigmoid(h);   // h * silu(h)
        if (cg == 0) op[(size_t)t * stp] = o;
    };

    // depth-8 pipeline: slots 0..6 preloaded with steps 0..6
    #pragma unroll
    for (int j = 0; j < 7; j++)
        loadStep(j, kS[j], qS[j], vS[j], aS[j]);

    for (int t = 0; t < T_STEPS; t += 8) {
        #pragma unroll
        for (int j = 0; j < 8; j++) {
            int tl = t + j + 7;
            if (tl > T_STEPS - 1) tl = T_STEPS - 1;
            const int ls = (j + 7) & 7;           // slot freed 8 steps ago
            loadStep(tl, kS[ls], qS[ls], vS[ls], aS[ls]);
            compute(t + j, kS[j], qS[j], vS[j], aS[j]);
        }
    }

    float* sfp = out + TBN + ((size_t)b * NST + row) * NST + c0;
    *(float4*)(sfp)     = make_float4(S[0], S[1], S[2], S[3]);
    *(float4*)(sfp + 4) = make_float4(S[4], S[5], S[6], S[7]);
}

// ======================= launch =======================

extern "C" void kernel_launch(void* const* d_in, const int* in_sizes, int n_in,
                              void* d_out, int out_size, void* d_ws, size_t ws_size,
                              hipStream_t stream)
{
    const float* x  = (const float*)d_in[0];
    const float* S0 = (const float*)d_in[1];
    const float* Wk = (const float*)d_in[2];
    const float* Wv = (const float*)d_in[3];
    const float* Wq = (const float*)d_in[4];
    const float* Wa = (const float*)d_in[5];
    const float* da = (const float*)d_in[6];
    const float* ba = (const float*)d_in[7];
    float* out = (float*)d_out;
    float* ws  = (float*)d_ws;   // 4 x [T,B,N] fp32 = 32 MiB

    dim3 gemm_grid((T_STEPS * BATCH) / MT, 2);
    proj_gemm_fused<<<gemm_grid, 128, 0, stream>>>(x, Wk, Wv, Wq, Wa, ws);

    scan8_kernel<<<dim3(BATCH * 8), 64, 0, stream>>>(ws, S0, da, ba, out);
}

// Round 4
// 567.106 us; speedup vs baseline: 1.1803x; 1.1803x over previous
//
#include <hip/hip_runtime.h>
#include <math.h>

#define T_STEPS 1024
#define BATCH   32
#define DIM     1024
#define NST     64
#define TBN     ((size_t)T_STEPS * BATCH * NST)   // 2M elements per projection

// ======================= Phase 1: fused projection GEMM =======================
// Round-2 proven config: 253 us, VALUBusy 54% (ds_read-throughput bound at 1B/FMA).
// Tile 128x128x32, 256 threads, per-thread 8x8. Grid (256,2) = 2 blocks/CU.

#define MT 128
#define NT 128
#define KT 32

__global__ __launch_bounds__(256, 2)
void proj_gemm_fused(const float* __restrict__ x,
                     const float* __restrict__ Wk,
                     const float* __restrict__ Wv,
                     const float* __restrict__ Wq,
                     const float* __restrict__ Wa,
                     float* __restrict__ ws)
{
    __shared__ float As[KT][MT + 4];
    __shared__ float Bs[KT][NT + 4];

    const int tid = threadIdx.x;
    const int m0  = blockIdx.x * MT;
    const int nb0 = blockIdx.y * NT;

    const int lm = tid >> 3;          // 0..31
    const int lk = (tid & 7) * 4;     // 0,4,...,28

    const int tm = (tid >> 4) * 8;
    const int tn = (tid & 15) * 8;

    const float* arow[4];
    const float* brow[4];
    #pragma unroll
    for (int p = 0; p < 4; p++) {
        arow[p] = x + (size_t)(m0 + p * 32 + lm) * DIM + lk;
        const int ng = nb0 + p * 32 + lm;
        const float* W = (ng < 64) ? Wk : (ng < 128) ? Wv : (ng < 192) ? Wq : Wa;
        brow[p] = W + (size_t)(ng & 63) * DIM + lk;
    }

    float acc[8][8];
    #pragma unroll
    for (int i = 0; i < 8; i++)
        #pragma unroll
        for (int j = 0; j < 8; j++) acc[i][j] = 0.f;

    for (int k0 = 0; k0 < DIM; k0 += KT) {
        __syncthreads();
        #pragma unroll
        for (int p = 0; p < 4; p++) {
            const int mm = p * 32 + lm;
            const float4 v = *(const float4*)(arow[p] + k0);
            As[lk + 0][mm] = v.x; As[lk + 1][mm] = v.y;
            As[lk + 2][mm] = v.z; As[lk + 3][mm] = v.w;
        }
        #pragma unroll
        for (int p = 0; p < 4; p++) {
            const int nn = p * 32 + lm;
            const float4 v = *(const float4*)(brow[p] + k0);
            Bs[lk + 0][nn] = v.x; Bs[lk + 1][nn] = v.y;
            Bs[lk + 2][nn] = v.z; Bs[lk + 3][nn] = v.w;
        }
        __syncthreads();

        #pragma unroll 4
        for (int kk = 0; kk < KT; kk++) {
            float a[8], b[8];
            *(float4*)&a[0] = *(const float4*)&As[kk][tm];
            *(float4*)&a[4] = *(const float4*)&As[kk][tm + 4];
            *(float4*)&b[0] = *(const float4*)&Bs[kk][tn];
            *(float4*)&b[4] = *(const float4*)&Bs[kk][tn + 4];
            #pragma unroll
            for (int i = 0; i < 8; i++)
                #pragma unroll
                for (int j = 0; j < 8; j++)
                    acc[i][j] = fmaf(a[i], b[j], acc[i][j]);
        }
    }

    const int ng0  = nb0 + tn;
    const int wsel = ng0 >> 6;
    const int nloc = ng0 & 63;
    float* ob = ws + (size_t)wsel * TBN + nloc;
    #pragma unroll
    for (int i = 0; i < 8; i++) {
        float* o = ob + (size_t)(m0 + tm + i) * NST;
        *(float4*)(o)     = make_float4(acc[i][0], acc[i][1], acc[i][2], acc[i][3]);
        *(float4*)(o + 4) = make_float4(acc[i][4], acc[i][5], acc[i][6], acc[i][7]);
    }
}

// ======================= Phase 2: sequential scan =======================
// 8 lanes/row, 8 cols/lane, wave = 8 rows, grid = 32 b x 8 rowgroups = 256 blocks.
// Fix for the register-spill stall: NO register prefetch arrays. Chunks of 16 steps
// staged through a double-buffered LDS tile. Per chunk: 9 coalesced float4 global
// loads -> regs (36 VGPR), compute 16 steps from current LDS buffer, ds_write regs
// into the other buffer, one barrier. Global latency amortized over ~2600 cyc.

#define CH 16            // steps per chunk
#define NCHUNK (T_STEPS / CH)

__device__ __forceinline__ float dpp_add_xor1(float v) {   // quad_perm [1,0,3,2]
    int o = __builtin_amdgcn_mov_dpp(__float_as_int(v), 0xB1, 0xF, 0xF, true);
    return v + __int_as_float(o);
}
__device__ __forceinline__ float dpp_add_xor2(float v) {   // quad_perm [2,3,0,1]
    int o = __builtin_amdgcn_mov_dpp(__float_as_int(v), 0x4E, 0xF, 0xF, true);
    return v + __int_as_float(o);
}
__device__ __forceinline__ float dpp_add_half_mirror(float v) { // ROW_HALF_MIRROR
    int o = __builtin_amdgcn_mov_dpp(__float_as_int(v), 0x141, 0xF, 0xF, true);
    return v + __int_as_float(o);
}

__device__ __forceinline__ float fast_sigmoid(float z) {
    float e = __builtin_amdgcn_exp2f(z * -1.44269504088896340736f);
    return __builtin_amdgcn_rcpf(1.0f + e);
}

__global__ __launch_bounds__(64)
void scan8_kernel(const float* __restrict__ ws,
                  const float* __restrict__ S0,
                  const float* __restrict__ d_alpha,
                  const float* __restrict__ b_alpha,
                  float* __restrict__ out)
{
    const float* kb = ws;
    const float* vb = ws + TBN;
    const float* qb = ws + 2 * TBN;
    const float* ab = ws + 3 * TBN;

    // LDS: kq[buf][s][0..63]=k_t, [64..127]=q_t ; va[buf][s][0..7]=v rows, [8..15]=a rows
    __shared__ float kq[2][CH][132];
    __shared__ float va[2][CH][16];

    const int lane = threadIdx.x;      // 0..63
    const int b    = blockIdx.x >> 3;  // batch
    const int rg   = blockIdx.x & 7;   // row group (8 rows)
    const int rl   = lane >> 3;        // row within group
    const int cg   = lane & 7;         // column group
    const int row  = rg * 8 + rl;      // 0..63
    const int c0   = cg * 8;

    float S[8];
    {
        const float* s0p = S0 + ((size_t)b * NST + row) * NST + c0;
        float4 v0 = *(const float4*)(s0p);
        float4 v1 = *(const float4*)(s0p + 4);
        S[0]=v0.x; S[1]=v0.y; S[2]=v0.z; S[3]=v0.w;
        S[4]=v1.x; S[5]=v1.y; S[6]=v1.z; S[7]=v1.w;
    }
    const float da = d_alpha[row];
    const float ba = b_alpha[row];

    const size_t stp = (size_t)BATCH * NST;   // 2048
    float* op = out + (size_t)b * NST + row;

    // ---- staging address precompute (per thread) ----
    // kq: 512 float4 per chunk; thread handles idx = p*64+lane, p=0..7.
    //     s = idx>>5, f = idx&31 ; f<16 -> k float4 #f, else q float4 #(f-16).
    //     LDS col = f*4 in both cases.
    int kq_s[8]; const float* kq_g[8];
    #pragma unroll
    for (int p = 0; p < 8; p++) {
        const int idx = p * 64 + lane;
        const int s   = idx >> 5;
        const int f   = idx & 31;
        kq_s[p] = s;
        const float* base = (f < 16) ? kb : qb;
        kq_g[p] = base + (size_t)s * stp + (size_t)b * NST + (f & 15) * 4;
    }
    // va: 64 float4 per chunk; thread handles s = lane>>2, w = lane&3.
    //     w<2 -> v rows (w*4..), w>=2 -> a rows ((w-2)*4..). LDS col = w*4.
    const int va_s = lane >> 2;
    const int va_w = lane & 3;
    const float* va_g = ((va_w < 2) ? vb : ab)
                      + (size_t)va_s * stp + (size_t)b * NST + rg * 8 + (va_w & 1) * 4;

    auto stage_issue = [&](int c, float4 (&rkq)[8], float4& rva) {
        const size_t off = (size_t)c * CH * stp;
        #pragma unroll
        for (int p = 0; p < 8; p++)
            rkq[p] = *(const float4*)(kq_g[p] + off);
        rva = *(const float4*)(va_g + off);
    };
    auto stage_write = [&](int nb, const float4 (&rkq)[8], const float4& rva) {
        #pragma unroll
        for (int p = 0; p < 8; p++) {
            const int f = (p * 64 + lane) & 31;
            *(float4*)&kq[nb][kq_s[p]][f * 4] = rkq[p];
        }
        *(float4*)&va[nb][va_s][va_w * 4] = rva;
    };

    // ---- prologue: chunk 0 into buffer 0 ----
    {
        float4 rkq[8]; float4 rva;
        stage_issue(0, rkq, rva);
        stage_write(0, rkq, rva);
    }
    __syncthreads();

    for (int c = 0; c < NCHUNK; c++) {
        const int cur = c & 1;
        const int nxt = cur ^ 1;

        // issue next chunk's global loads early (latency hidden under compute)
        float4 rkq[8]; float4 rva;
        const int cn = (c + 1 < NCHUNK) ? c + 1 : c;   // tail: harmless reload
        stage_issue(cn, rkq, rva);

        // compute CH steps from the current LDS buffer
        #pragma unroll
        for (int s = 0; s < CH; s++) {
            float kf[8], qf[8];
            *(float4*)&kf[0] = *(const float4*)&kq[cur][s][c0];
            *(float4*)&kf[4] = *(const float4*)&kq[cur][s][c0 + 4];
            *(float4*)&qf[0] = *(const float4*)&kq[cur][s][64 + c0];
            *(float4*)&qf[4] = *(const float4*)&kq[cur][s][64 + c0 + 4];
            const float vv = va[cur][s][rl];
            const float aa = va[cur][s][8 + rl] + ba;

            float p0 = S[0] * kf[0];
            float p1 = S[1] * kf[1];
            p0 = fmaf(S[2], kf[2], p0);  p1 = fmaf(S[3], kf[3], p1);
            p0 = fmaf(S[4], kf[4], p0);  p1 = fmaf(S[5], kf[5], p1);
            p0 = fmaf(S[6], kf[6], p0);  p1 = fmaf(S[7], kf[7], p1);
            float part = p0 + p1;
            part = dpp_add_xor1(part);
            part = dpp_add_xor2(part);
            part = dpp_add_half_mirror(part);

            const float z     = fmaf(da, part, aa);
            const float alpha = fast_sigmoid(z);
            const float w     = (1.f - alpha) * vv;

            #pragma unroll
            for (int j = 0; j < 8; j++)
                S[j] = fmaf(alpha, S[j], w * kf[j]);

            float h0 = S[0] * qf[0];
            float h1 = S[1] * qf[1];
            h0 = fmaf(S[2], qf[2], h0);  h1 = fmaf(S[3], qf[3], h1);
            h0 = fmaf(S[4], qf[4], h0);  h1 = fmaf(S[5], qf[5], h1);
            h0 = fmaf(S[6], qf[6], h0);  h1 = fmaf(S[7], qf[7], h1);
            float h = h0 + h1;
            h = dpp_add_xor1(h);
            h = dpp_add_xor2(h);
            h = dpp_add_half_mirror(h);

            const float o = h * h * fast_sigmoid(h);   // h * silu(h)
            if (cg == 0) op[(size_t)(c * CH + s) * stp] = o;
        }

        // write next chunk into the other buffer, one barrier per chunk
        stage_write(nxt, rkq, rva);
        __syncthreads();
    }

    float* sfp = out + TBN + ((size_t)b * NST + row) * NST + c0;
    *(float4*)(sfp)     = make_float4(S[0], S[1], S[2], S[3]);
    *(float4*)(sfp + 4) = make_float4(S[4], S[5], S[6], S[7]);
}

// ======================= launch =======================

extern "C" void kernel_launch(void* const* d_in, const int* in_sizes, int n_in,
                              void* d_out, int out_size, void* d_ws, size_t ws_size,
                              hipStream_t stream)
{
    const float* x  = (const float*)d_in[0];
    const float* S0 = (const float*)d_in[1];
    const float* Wk = (const float*)d_in[2];
    const float* Wv = (const float*)d_in[3];
    const float* Wq = (const float*)d_in[4];
    const float* Wa = (const float*)d_in[5];
    const float* da = (const float*)d_in[6];
    const float* ba = (const float*)d_in[7];
    float* out = (float*)d_out;
    float* ws  = (float*)d_ws;   // 4 x [T,B,N] fp32 = 32 MiB

    dim3 gemm_grid((T_STEPS * BATCH) / MT, 2);
    proj_gemm_fused<<<gemm_grid, 256, 0, stream>>>(x, Wk, Wv, Wq, Wa, ws);

    scan8_kernel<<<dim3(BATCH * 8), 64, 0, stream>>>(ws, S0, da, ba, out);
}

// Round 6
// 443.208 us; speedup vs baseline: 1.5103x; 1.2795x over previous
//
#include <hip/hip_runtime.h>
#include <math.h>

#define T_STEPS 1024
#define BATCH   32
#define DIM     1024
#define NST     64
#define TBN     ((size_t)T_STEPS * BATCH * NST)   // 2M elements per projection

typedef __attribute__((ext_vector_type(8))) short bf16x8;
typedef __attribute__((ext_vector_type(4))) float f32x4;

// ======================= Phase 1: bf16 hi/lo split MFMA GEMM =======================
// out[m][nf] = sum_d x[m][d]*Wf[nf][d], M=32768, Nf=256, K=1024, fp32 in/out.
// x = hi + lo (bf16 truncation split); x.W ~= hi.Whi + hi.Wlo + lo.Whi (lo.lo ~2^-16, dropped).
// Tile 64(M) x 256(N) x 32(K); 256 threads = 4 waves; wave w owns n in [64w,64w+64)
// == projection w exactly. mfma_f32_16x16x32_bf16, per wave 4x4 tiles of 16x16.
// Grid 512 = 2 blocks/CU.

__device__ __forceinline__ void cvt_hi_lo(const float4& v0, const float4& v1,
                                          uint4& hi, uint4& lo)
{
    float f[8] = {v0.x, v0.y, v0.z, v0.w, v1.x, v1.y, v1.z, v1.w};
    unsigned hb[8], lb[8];
    #pragma unroll
    for (int i = 0; i < 8; i++) {
        unsigned bits = __float_as_uint(f[i]);
        hb[i] = bits & 0xffff0000u;                       // hi = truncate to bf16
        lb[i] = __float_as_uint(f[i] - __uint_as_float(hb[i]));  // exact residual
    }
    hi.x = (hb[0] >> 16) | hb[1];
    hi.y = (hb[2] >> 16) | hb[3];
    hi.z = (hb[4] >> 16) | hb[5];
    hi.w = (hb[6] >> 16) | hb[7];
    lo.x = (lb[0] >> 16) | (lb[1] & 0xffff0000u);
    lo.y = (lb[2] >> 16) | (lb[3] & 0xffff0000u);
    lo.z = (lb[4] >> 16) | (lb[5] & 0xffff0000u);
    lo.w = (lb[6] >> 16) | (lb[7] & 0xffff0000u);
}

__global__ __launch_bounds__(256, 2)
void proj_gemm_mfma(const float* __restrict__ x,
                    const float* __restrict__ Wk,
                    const float* __restrict__ Wv,
                    const float* __restrict__ Wq,
                    const float* __restrict__ Wa,
                    float* __restrict__ ws)
{
    __shared__ short Ahi[64][32],  Alo[64][32];    // 4 KB each
    __shared__ short Bhi[256][32], Blo[256][32];   // 16 KB each -> 40 KB total

    const int tid  = threadIdx.x;
    const int lane = tid & 63;
    const int wave = tid >> 6;          // 0..3 == projection selector
    const int m0   = blockIdx.x * 64;

    // staging: thread covers row am, k-range [ak, ak+8)
    const int am = tid >> 2;            // 0..63
    const int ak = (tid & 3) * 8;       // 0,8,16,24
    const float* agp = x + (size_t)(m0 + am) * DIM + ak;

    const float* bgp[4];
    #pragma unroll
    for (int p = 0; p < 4; p++) {
        const int n = p * 64 + am;      // fused col 0..255
        const float* W = (n < 64) ? Wk : (n < 128) ? Wv : (n < 192) ? Wq : Wa;
        bgp[p] = W + (size_t)(n & 63) * DIM + ak;
    }

    // MFMA fragment ids (A-frag: A[m=lane&15][k=(lane>>4)*8+j], B-frag same on W rows)
    const int fr = lane & 15;
    const int fk = (lane >> 4) * 8;

    f32x4 acc[4][4];
    #pragma unroll
    for (int i = 0; i < 4; i++)
        #pragma unroll
        for (int j = 0; j < 4; j++)
            acc[i][j] = (f32x4)0.0f;

    // preload K-block 0
    float4 ar0 = *(const float4*)(agp);
    float4 ar1 = *(const float4*)(agp + 4);
    float4 br0[4], br1[4];
    #pragma unroll
    for (int p = 0; p < 4; p++) {
        br0[p] = *(const float4*)(bgp[p]);
        br1[p] = *(const float4*)(bgp[p] + 4);
    }

    #pragma unroll 1
    for (int kb = 0; kb < 32; kb++) {
        __syncthreads();   // prev compute done reading LDS
        {
            uint4 hi, lo;
            cvt_hi_lo(ar0, ar1, hi, lo);
            *(uint4*)&Ahi[am][ak] = hi;
            *(uint4*)&Alo[am][ak] = lo;
            #pragma unroll
            for (int p = 0; p < 4; p++) {
                cvt_hi_lo(br0[p], br1[p], hi, lo);
                *(uint4*)&Bhi[p * 64 + am][ak] = hi;
                *(uint4*)&Blo[p * 64 + am][ak] = lo;
            }
        }
        __syncthreads();   // tiles ready

        // issue next K-block's global loads; they fly under the MFMAs
        {
            const int kn = (kb + 1 < 32) ? (kb + 1) * 32 : kb * 32;
            ar0 = *(const float4*)(agp + kn);
            ar1 = *(const float4*)(agp + kn + 4);
            #pragma unroll
            for (int p = 0; p < 4; p++) {
                br0[p] = *(const float4*)(bgp[p] + kn);
                br1[p] = *(const float4*)(bgp[p] + kn + 4);
            }
        }

        bf16x8 ah[4], al[4], bh[4], bl[4];
        #pragma unroll
        for (int mt = 0; mt < 4; mt++) {
            ah[mt] = *(const bf16x8*)&Ahi[mt * 16 + fr][fk];
            al[mt] = *(const bf16x8*)&Alo[mt * 16 + fr][fk];
        }
        #pragma unroll
        for (int nt = 0; nt < 4; nt++) {
            const int n = wave * 64 + nt * 16 + fr;
            bh[nt] = *(const bf16x8*)&Bhi[n][fk];
            bl[nt] = *(const bf16x8*)&Blo[n][fk];
        }
        #pragma unroll
        for (int mt = 0; mt < 4; mt++)
            #pragma unroll
            for (int nt = 0; nt < 4; nt++) {
                acc[mt][nt] = __builtin_amdgcn_mfma_f32_16x16x32_bf16(ah[mt], bh[nt], acc[mt][nt], 0, 0, 0);
                acc[mt][nt] = __builtin_amdgcn_mfma_f32_16x16x32_bf16(al[mt], bh[nt], acc[mt][nt], 0, 0, 0);
                acc[mt][nt] = __builtin_amdgcn_mfma_f32_16x16x32_bf16(ah[mt], bl[nt], acc[mt][nt], 0, 0, 0);
            }
    }

    // epilogue: C/D layout col = lane&15 (n), row = (lane>>4)*4 + reg (m)
    float* outb = ws + (size_t)wave * TBN;
    const int r0 = (lane >> 4) * 4;
    #pragma unroll
    for (int mt = 0; mt < 4; mt++)
        #pragma unroll
        for (int nt = 0; nt < 4; nt++)
            #pragma unroll
            for (int r = 0; r < 4; r++)
                outb[(size_t)(m0 + mt * 16 + r0 + r) * NST + nt * 16 + fr] = acc[mt][nt][r];
}

// ======================= Phase 2: sequential scan, short-chain form =======================
// Algebraic pipeline: ret_{t+1} = S_t.k_{t+1} = a_t*(S_{t-1}.k_{t+1}) + (1-a_t)*v_t*(k_t.k_{t+1})
// Both dots use OLD S / preloaded k => off the recurrence chain; on-chain = fma->sigmoid->fma.
// 16 lanes/row, 4 cols/lane, wave = 4 rows; grid = 32 b x 16 rowgroups = 512 blocks (2 waves/CU).
// LDS double-buffered 16-step chunks; single wave per block => no barriers needed.

template <int CTRL>
__device__ __forceinline__ float dpp_add(float v) {
    int o = __builtin_amdgcn_mov_dpp(__float_as_int(v), CTRL, 0xF, 0xF, true);
    return v + __int_as_float(o);
}
__device__ __forceinline__ float reduce16(float v) {
    v = dpp_add<0xB1>(v);     // quad_perm [1,0,3,2]
    v = dpp_add<0x4E>(v);     // quad_perm [2,3,0,1]
    v = dpp_add<0x141>(v);    // ROW_HALF_MIRROR (xor within 8)
    v = dpp_add<0x140>(v);    // ROW_MIRROR (combine halves of 16)
    return v;
}
__device__ __forceinline__ float fast_sigmoid(float z) {
    float e = __builtin_amdgcn_exp2f(z * -1.44269504088896340736f);
    return __builtin_amdgcn_rcpf(1.0f + e);
}

#define SCH 16
#define NCH (T_STEPS / SCH)

__global__ __launch_bounds__(64, 1)
void scan16_kernel(const float* __restrict__ ws,
                   const float* __restrict__ S0,
                   const float* __restrict__ d_alpha,
                   const float* __restrict__ b_alpha,
                   float* __restrict__ out)
{
    const float* kb_ = ws;
    const float* vb_ = ws + TBN;
    const float* qb_ = ws + 2 * TBN;
    const float* ab_ = ws + 3 * TBN;

    __shared__ float kq[2][SCH][128];   // [0..63]=k_t, [64..127]=q_t
    __shared__ float va[2][SCH][8];     // [0..3]=v rows, [4..7]=ax rows

    const int lane = threadIdx.x;
    const int b    = blockIdx.x >> 4;   // batch
    const int rg   = blockIdx.x & 15;   // row group (4 rows)
    const int rl   = lane >> 4;         // 0..3 row within group
    const int cl   = lane & 15;         // column lane
    const int row  = rg * 4 + rl;
    const int c0   = cl * 4;

    float S[4];
    {
        float4 sv = *(const float4*)(S0 + ((size_t)b * NST + row) * NST + c0);
        S[0] = sv.x; S[1] = sv.y; S[2] = sv.z; S[3] = sv.w;
    }
    const float da  = d_alpha[row];
    const float bav = b_alpha[row];

    const size_t stp = (size_t)BATCH * NST;   // 2048

    // staging maps: kq = 512 float4/chunk, 8 per lane; va = 32 float4, lanes<32
    int kqs[8], kqf[8];
    const float* kqg[8];
    #pragma unroll
    for (int p = 0; p < 8; p++) {
        const int idx = p * 64 + lane;
        const int s   = idx >> 5;
        const int f   = idx & 31;
        kqs[p] = s; kqf[p] = f;
        kqg[p] = ((f < 16) ? kb_ : qb_) + (size_t)s * stp + (size_t)b * NST + (f & 15) * 4;
    }
    const int vas = (lane & 31) >> 1;
    const int vaw = lane & 1;
    const float* vag = (vaw ? ab_ : vb_) + (size_t)vas * stp + (size_t)b * NST + rg * 4;

    auto issue = [&](int ch, float4 (&rk)[8], float4& rv) {
        const size_t off = (size_t)ch * SCH * stp;
        #pragma unroll
        for (int p = 0; p < 8; p++)
            rk[p] = *(const float4*)(kqg[p] + off);
        rv = *(const float4*)(vag + off);
    };
    auto commit = [&](int bi, const float4 (&rk)[8], const float4& rv) {
        #pragma unroll
        for (int p = 0; p < 8; p++)
            *(float4*)&kq[bi][kqs[p]][kqf[p] * 4] = rk[p];
        if (lane < 32)
            *(float4*)&va[bi][vas][vaw * 4] = rv;
    };

    // prologue: chunks 0,1 resident
    {
        float4 rk[8]; float4 rv;
        issue(0, rk, rv); commit(0, rk, rv);
        issue(1, rk, rv); commit(1, rk, rv);
    }

    float kcur[4];
    *(float4*)kcur = *(const float4*)&kq[0][0][c0];

    // ret_0 = S0 . k_0
    float ret;
    {
        float p0 = S[0] * kcur[0];
        p0 = fmaf(S[1], kcur[1], p0);
        p0 = fmaf(S[2], kcur[2], p0);
        p0 = fmaf(S[3], kcur[3], p0);
        ret = reduce16(p0);
    }

    float* op = out + (size_t)b * NST + row;

    for (int ch = 0; ch < NCH; ch++) {
        const int cur = ch & 1, nxt = cur ^ 1;

        float4 rk[8]; float4 rv;
        const int cn = (ch + 2 < NCH) ? ch + 2 : NCH - 1;
        issue(cn, rk, rv);   // global loads fly under the 16-step compute

        #pragma unroll
        for (int s = 0; s < SCH; s++) {
            const int t = ch * SCH + s;
            float qf[4], knx[4];
            *(float4*)qf = *(const float4*)&kq[cur][s][64 + c0];
            if (s < SCH - 1) *(float4*)knx = *(const float4*)&kq[cur][s + 1][c0];
            else             *(float4*)knx = *(const float4*)&kq[nxt][0][c0];
            const float vv = va[cur][s][rl];
            const float aa = va[cur][s][4 + rl] + bav;

            // --- recurrence chain: fma -> sigmoid ---
            const float z     = fmaf(da, ret, aa);
            const float alpha = fast_sigmoid(z);

            // --- shadow dots (old S, preloaded k's) ---
            float d1 = S[0] * knx[0];
            d1 = fmaf(S[1], knx[1], d1);
            d1 = fmaf(S[2], knx[2], d1);
            d1 = fmaf(S[3], knx[3], d1);
            d1 = reduce16(d1);                 // S_{t-1} . k_{t+1}
            float d2 = kcur[0] * knx[0];
            d2 = fmaf(kcur[1], knx[1], d2);
            d2 = fmaf(kcur[2], knx[2], d2);
            d2 = fmaf(kcur[3], knx[3], d2);
            d2 = reduce16(d2);                 // k_t . k_{t+1}

            // --- S update ---
            const float w = (1.f - alpha) * vv;
            S[0] = fmaf(alpha, S[0], w * kcur[0]);
            S[1] = fmaf(alpha, S[1], w * kcur[1]);
            S[2] = fmaf(alpha, S[2], w * kcur[2]);
            S[3] = fmaf(alpha, S[3], w * kcur[3]);

            // --- next ret (one fma after alpha) ---
            const float c2v = vv * d2;
            ret = fmaf(alpha, d1 - c2v, c2v);

            // --- output ---
            float h = S[0] * qf[0];
            h = fmaf(S[1], qf[1], h);
            h = fmaf(S[2], qf[2], h);
            h = fmaf(S[3], qf[3], h);
            h = reduce16(h);
            const float o = h * h * fast_sigmoid(h);   // h * silu(h)
            if (cl == 0) op[(size_t)t * stp] = o;

            kcur[0] = knx[0]; kcur[1] = knx[1];
            kcur[2] = knx[2]; kcur[3] = knx[3];
        }

        commit(cur, rk, rv);   // chunk ch+2 into the buffer chunk ch vacated
    }

    // S_final
    float* sfp = out + TBN + ((size_t)b * NST + row) * NST + c0;
    *(float4*)sfp = make_float4(S[0], S[1], S[2], S[3]);
}

// ======================= launch =======================

extern "C" void kernel_launch(void* const* d_in, const int* in_sizes, int n_in,
                              void* d_out, int out_size, void* d_ws, size_t ws_size,
                              hipStream_t stream)
{
    const float* x  = (const float*)d_in[0];
    const float* S0 = (const float*)d_in[1];
    const float* Wk = (const float*)d_in[2];
    const float* Wv = (const float*)d_in[3];
    const float* Wq = (const float*)d_in[4];
    const float* Wa = (const float*)d_in[5];
    const float* da = (const float*)d_in[6];
    const float* ba = (const float*)d_in[7];
    float* out = (float*)d_out;
    float* ws  = (float*)d_ws;   // 4 x [T,B,N] fp32 = 32 MiB

    proj_gemm_mfma<<<dim3((T_STEPS * BATCH) / 64), 256, 0, stream>>>(x, Wk, Wv, Wq, Wa, ws);

    scan16_kernel<<<dim3(BATCH * 16), 64, 0, stream>>>(ws, S0, da, ba, out);
}